// Round 10
// baseline (296.059 us; speedup 1.0000x reference)
//
#include <hip/hip_runtime.h>

#define HW 3136
#define NB 8
#define CD 128
#define NT (HW/64)
// C^-0.5 * log2(e), folded into the Q projection so attn can use exp2 directly
#define QSCALE 0.12751750206f

typedef __attribute__((ext_vector_type(8))) short short8;
typedef __attribute__((ext_vector_type(4))) short short4v;
typedef __attribute__((ext_vector_type(4))) float floatx4;
typedef __attribute__((ext_vector_type(4))) unsigned short ushort4v;

static __device__ __forceinline__ unsigned short f2b(float f){
  union { float f; unsigned u; } v; v.f = f;
  unsigned r = v.u + 0x7FFFu + ((v.u >> 16) & 1u);
  return (unsigned short)(r >> 16);
}
static __device__ __forceinline__ float b2f(unsigned short h){
  union { unsigned u; float f; } v; v.u = ((unsigned)h) << 16;
  return v.f;
}
// packed f32x2 -> bf16x2 (RNE), 1 instr vs 3 bitops; no builtin on gfx950
static __device__ __forceinline__ unsigned cvtpk(float lo, float hi){
  unsigned r;
  asm("v_cvt_pk_bf16_f32 %0, %1, %2" : "=v"(r) : "v"(lo), "v"(hi));
  return r;
}

// K=16 bf16 MFMA: builtin spelling differs across ROCm versions; hedge.
#if __has_builtin(__builtin_amdgcn_mfma_f32_16x16x16bf16_1k)
#define MFMA16(a,b,c) __builtin_amdgcn_mfma_f32_16x16x16bf16_1k(a,b,c,0,0,0)
#elif __has_builtin(__builtin_amdgcn_mfma_f32_16x16x16_bf16)
#define MFMA16(a,b,c) __builtin_amdgcn_mfma_f32_16x16x16_bf16(a,b,c,0,0,0)
#else
static __device__ __forceinline__ floatx4 mfma16_asm(short4v a, short4v b, floatx4 c){
  floatx4 d;
  asm volatile("v_mfma_f32_16x16x16_bf16 %0, %1, %2, %3\n\ts_nop 7\n\ts_nop 7"
               : "=v"(d) : "v"(a), "v"(b), "v"(c));
  return d;
}
#define MFMA16(a,b,c) mfma16_asm(a,b,c)
#endif

// ---------------------------------------------------------------------------
// One-time W f32->bf16 conversion (3 blocks; R6-proven ~null cost).
// ---------------------------------------------------------------------------
__global__ __launch_bounds__(256) void wconv_kernel(
    const float* __restrict__ wq, const float* __restrict__ wk,
    const float* __restrict__ wv, unsigned short* __restrict__ Wb)
{
  const float* src = blockIdx.x==0 ? wq : (blockIdx.x==1 ? wk : wv);
  unsigned short* dst = Wb + (size_t)blockIdx.x*CD*CD;
  for (int i = threadIdx.x; i < CD*CD/8; i += 256){
    floatx4 v0 = *(const floatx4*)(src + (size_t)i*8);
    floatx4 v1 = *(const floatx4*)(src + (size_t)i*8 + 4);
    union { unsigned u[4]; ushort4v p[2]; } pk;
    pk.u[0] = cvtpk(v0[0], v0[1]);
    pk.u[1] = cvtpk(v0[2], v0[3]);
    pk.u[2] = cvtpk(v1[0], v1[1]);
    pk.u[3] = cvtpk(v1[2], v1[3]);
    *(ushort4v*)(dst + (size_t)i*8)     = pk.p[0];
    *(ushort4v*)(dst + (size_t)i*8 + 4) = pk.p[1];
  }
}

// ---------------------------------------------------------------------------
// 1x1 conv projections, zero-LDS edition.
// R9 ledger: proj ~100-105us vs ~20us traffic floor; eliminations say not
// W-traffic (R6), not occupancy (R6), not stores (R8) -> the X^T LDS
// round-trip (conflict-heavy scalar transpose + barrier) is what's left.
// Fix: MFMA A- and B-frag layouts are IDENTICAL (lane m -> row/col,
// k = dk*32+quad*8+j), so X frags load DIRECTLY from global X[c][hw]:
// 8 scalars at stride HW, 4x64B coalesced segments per instruction (unlike
// R5's 16-segment gather), packed via cvtpk. Same xf registers serve K-jobs
// as B (mfma(wf,xf) -> D[o][hw], R8 K path) and V-jobs as A (mfma(xf,wf) ->
// D[hw][c], R8 V path). W pre-converted bf16, b128 from L2. No LDS, no
// barrier, ~60 VGPR -> 8 waves/SIMD, all 1960 blocks resident, HBM-streaming.
// ---------------------------------------------------------------------------
__global__ __launch_bounds__(256) void proj_kernel(
    const float* __restrict__ s, const float* __restrict__ t1, const float* __restrict__ t2,
    const float* __restrict__ bq, const float* __restrict__ bk, const float* __restrict__ bv,
    const unsigned short* __restrict__ Wb,
    unsigned short* __restrict__ qkv)
{
  const int job = blockIdx.z;
  const float* x; const float* bias; float scl; int cmajor; size_t dstoff; int wsel;
  switch(job){
    case 0: x=s;  wsel=0; bias=bq; scl=QSCALE; cmajor=0; dstoff=0; break;
    case 1: x=t1; wsel=1; bias=bk; scl=1.f;    cmajor=0; dstoff=1; break;
    case 2: x=t1; wsel=2; bias=bv; scl=1.f;    cmajor=1; dstoff=2; break;
    case 3: x=t2; wsel=1; bias=bk; scl=1.f;    cmajor=0; dstoff=3; break;
    default:x=t2; wsel=2; bias=bv; scl=1.f;    cmajor=1; dstoff=4; break;
  }
  const size_t TS = (size_t)NB*HW*CD;
  const int b   = blockIdx.y;
  const int hw0 = blockIdx.x * 64;
  const int tid = threadIdx.x;
  const int m = tid & 15, quad = (tid >> 4) & 3, wv_ = tid >> 6;
  const int hw = hw0 + wv_*16 + m;

  // X fragments direct from global (no transpose, no LDS):
  // xf[dk] element j  <->  X[c = dk*32 + quad*8 + j][hw]
  const float* xb = x + (size_t)b*CD*HW + (size_t)quad*8*HW + hw;
  short8 xf[4];
#pragma unroll
  for (int dk=0;dk<4;dk++){
    union { unsigned u[4]; short8 s8; } p;
#pragma unroll
    for (int w=0;w<4;w++){
      float v0 = xb[(size_t)(dk*32 + 2*w    )*HW];
      float v1 = xb[(size_t)(dk*32 + 2*w + 1)*HW];
      p.u[w] = cvtpk(v0, v1);
    }
    xf[dk] = p.s8;
  }

  const unsigned short* W = Wb + (size_t)wsel*CD*CD;
  if (!cmajor){
    // K-type: D = mfma(W, X) = [o][hw]; lane: o = nt*16+quad*4+r, col hw = hw
    unsigned short* dstK = qkv + dstoff*TS + (size_t)b*HW*CD;
#pragma unroll
    for (int nt=0;nt<8;nt++){
      floatx4 acc = *(const floatx4*)(bias + nt*16 + quad*4);
#pragma unroll
      for (int dk=0;dk<4;dk++){
        short8 wf = *(const short8*)&W[(size_t)(nt*16 + m)*CD + dk*32 + quad*8];
        acc = __builtin_amdgcn_mfma_f32_16x16x32_bf16(wf, xf[dk], acc, 0,0,0);
      }
      union { unsigned u[2]; ushort4v p; } pk;
      pk.u[0] = cvtpk(acc[0]*scl, acc[1]*scl);
      pk.u[1] = cvtpk(acc[2]*scl, acc[3]*scl);
      *(ushort4v*)&dstK[(size_t)hw*CD + nt*16 + quad*4] = pk.p;
    }
  } else {
    // V-type: D = mfma(X, W) = [hw][c]; lane: hw = hw0+wv*16+quad*4+r, c = nt*16+m
    unsigned short* dstV = qkv + dstoff*TS + (size_t)b*CD*HW;
#pragma unroll
    for (int nt=0;nt<8;nt++){
      float bb = bias[nt*16 + m];
      floatx4 acc = {bb,bb,bb,bb};
#pragma unroll
      for (int dk=0;dk<4;dk++){
        short8 wf = *(const short8*)&W[(size_t)(nt*16 + m)*CD + dk*32 + quad*8];
        acc = __builtin_amdgcn_mfma_f32_16x16x32_bf16(xf[dk], wf, acc, 0,0,0);
      }
      union { unsigned u[2]; ushort4v p; } pk;
      pk.u[0] = cvtpk(acc[0], acc[1]);
      pk.u[1] = cvtpk(acc[2], acc[3]);
      *(ushort4v*)&dstV[(size_t)(nt*16 + m)*HW + hw0 + wv_*16 + quad*4] = pk.p;
    }
  }
}

// ---------------------------------------------------------------------------
// Flash attention — byte-frozen R9 (verified 144.5us; T5 setprio + T12 cvtpk).
// ---------------------------------------------------------------------------
__global__ __launch_bounds__(256,2) void attn_kernel(
    const unsigned short* __restrict__ qkv,
    unsigned short* __restrict__ Og)
{
  // shorts: K0 [0,8192) V0 [8192,16384) K1 [16384,24576) V1 [24576,32768)
  __shared__ __align__(16) unsigned short smem[32768 + 512 + 128]; // 66816 B
  float* lrb  = (float*)(smem + 32768);        // [4 wv][64 q]
  float* invL = (float*)(smem + 32768 + 512);  // [64 q]

  const int l  = blockIdx.x;       // 392 = 8 XCD-pinned b values x 49 qt
  const int b  = l & 7;
  const int qt = l >> 3;
  const size_t TS = (size_t)NB*HW*CD;
  const unsigned short* Q = qkv + (size_t)b*HW*CD;

  const int tid  = threadIdx.x;
  const int wv_  = tid >> 6;
  const int lane = tid & 63;
  const int m    = lane & 15;
  const int quad = lane >> 4;
  const int q0   = qt*64;

  // DMA source offsets (shorts), pre-swizzled so linear LDS dest + swizzled
  // ds_read agree: LDS(row, col16) holds logical col16 ^ (row&7).
  unsigned koff[4];
  {
    const int kr_ = lane >> 4, kc_ = lane & 15;
#pragma unroll
    for (int i=0;i<4;i++){
      const int krow = wv_*16 + i*4 + kr_;
      koff[i] = (unsigned)(krow*CD + ((kc_ ^ ((i*4 + kr_) & 7))*8));
    }
  }
  const int      vrow0 = wv_*32 + (lane>>3);
  const unsigned vcs   = (unsigned)(((lane&7) ^ (lane>>3))*8);

  // Q B-fragments, iter- and teacher-invariant
  short8 qf[4][4];
#pragma unroll
  for (int qs=0;qs<4;qs++){
    const unsigned short* qr = Q + (size_t)(q0 + qs*16 + m)*CD + quad*8;
#pragma unroll
    for (int dk=0;dk<4;dk++) qf[qs][dk] = *(const short8*)(qr + dk*32);
  }

#define STAGE(buf, ktile) do { \
    const unsigned short* kt_src = K + (size_t)(ktile)*64*CD; \
    const unsigned short* vt_src = V + (size_t)(ktile)*64; \
    unsigned short* kl = (unsigned short*)smem + (buf)*16384 + wv_*2048; \
    unsigned short* vl = (unsigned short*)smem + (buf)*16384 + 8192 + wv_*2048; \
    _Pragma("unroll") \
    for (int i_=0;i_<4;i_++) \
      __builtin_amdgcn_global_load_lds( \
        (const __attribute__((address_space(1))) void*)(kt_src + koff[i_]), \
        (__attribute__((address_space(3))) void*)(kl + i_*512), 16, 0, 0); \
    _Pragma("unroll") \
    for (int i_=0;i_<4;i_++) \
      __builtin_amdgcn_global_load_lds( \
        (const __attribute__((address_space(1))) void*)(vt_src + (size_t)(vrow0 + i_*8)*HW + vcs), \
        (__attribute__((address_space(3))) void*)(vl + i_*512), 16, 0, 0); \
  } while(0)

  for (int t2=0; t2<2; t2++){
    const unsigned short* K = qkv + TS*(size_t)(1 + 2*t2) + (size_t)b*HW*CD;
    const unsigned short* V = qkv + TS*(size_t)(2 + 2*t2) + (size_t)b*CD*HW;

    floatx4 Oc[8][4];                  // k-partial O^T: [ct][qs] (AGPRs)
#pragma unroll
    for (int i=0;i<8;i++)
#pragma unroll
      for (int j=0;j<4;j++) Oc[i][j] = (floatx4)0.f;
    float lr[4] = {0.f,0.f,0.f,0.f};

    STAGE(0, 0);                       // prologue: tile 0 -> buf0

    for (int kt = 0; kt < NT; kt++){
      const int cur = kt & 1;
      __builtin_amdgcn_s_barrier();    // B1: all waves done computing buf[cur^1]
      if (kt < NT-1){
        STAGE(cur^1, kt+1);            // async DMA next tile
        asm volatile("s_waitcnt vmcnt(8)" ::: "memory");  // own buf[cur] DMAs done
      } else {
        asm volatile("s_waitcnt vmcnt(0)" ::: "memory");
      }
      __builtin_amdgcn_sched_barrier(0);
      __builtin_amdgcn_s_barrier();    // B2: everyone's buf[cur] complete
      asm volatile("" ::: "memory");

      const unsigned short* Kc = (const unsigned short*)smem + cur*16384;
      const unsigned short* Vc = (const unsigned short*)smem + cur*16384 + 8192;

      // QK: S^T[wv's 16k][64q]; A-frag = own-wave K rows, swizzled read
      short8 af[4];
#pragma unroll
      for (int dk=0;dk<4;dk++)
        af[dk] = *(const short8*)&Kc[(wv_*16 + m)*128 + (((dk*4 + quad) ^ (m & 7))*8)];

      short4v pfv[4];
#pragma unroll
      for (int qs=0;qs<4;qs++){
        floatx4 acc = (floatx4)0.f;
        __builtin_amdgcn_s_setprio(1);           // T5: MFMA cluster priority
#pragma unroll
        for (int dk=0;dk<4;dk++)
          acc = __builtin_amdgcn_mfma_f32_16x16x32_bf16(af[dk], qf[qs][dk], acc, 0,0,0);
        __builtin_amdgcn_s_setprio(0);           // exp2 phase at low prio
        float c0 = __builtin_amdgcn_exp2f(acc[0]);
        float c1 = __builtin_amdgcn_exp2f(acc[1]);
        float c2 = __builtin_amdgcn_exp2f(acc[2]);
        float c3 = __builtin_amdgcn_exp2f(acc[3]);
        lr[qs] += (c0 + c1) + (c2 + c3);
        union { unsigned u[2]; short4v s; } pk;
        pk.u[0] = cvtpk(c0, c1);                 // T12: packed RNE convert
        pk.u[1] = cvtpk(c2, c3);
        pfv[qs] = pk.s;
      }

      // PV (K=16): O^T += V^T[c][wv's 16k] * P^T; swizzled b64 A-frag reads
      __builtin_amdgcn_s_setprio(1);             // T5: PV MFMA cluster
#pragma unroll
      for (int ct=0;ct<8;ct++){
        short4v vf = *(const short4v*)&Vc[(ct*16 + m)*64 +
                       (((2*wv_ + (quad>>1)) ^ (m & 7))*8) + (quad&1)*4];
#pragma unroll
        for (int qs=0;qs<4;qs++)
          Oc[ct][qs] = MFMA16(vf, pfv[qs], Oc[ct][qs]);
      }
      __builtin_amdgcn_s_setprio(0);
    }

    // ---- epilogue: cross-wave reduction of lr and O partials ----
#pragma unroll
    for (int qs=0;qs<4;qs++){
      lr[qs] += __shfl_xor(lr[qs], 16, 64);
      lr[qs] += __shfl_xor(lr[qs], 32, 64);
    }
    if (quad == 0){
#pragma unroll
      for (int qs=0;qs<4;qs++) lrb[wv_*64 + qs*16 + m] = lr[qs];
    }
    __syncthreads();
    if (tid < 64)
      invL[tid] = 1.f/(lrb[tid] + lrb[64+tid] + lrb[128+tid] + lrb[192+tid]);
    __syncthreads();

    float* Of = (float*)smem;          // overlaps K/V buffers (all reads done)
    unsigned short* ob = Og + ((size_t)t2*NB + b)*HW*CD + (size_t)q0*CD;
    const int qlr = wv_*16 + (lane>>2);
    const int c8  = (lane&3)*8;
#pragma unroll
    for (int rd=0; rd<4; rd++){
#pragma unroll
      for (int cc=0; cc<2; cc++){
#pragma unroll
        for (int qs=0; qs<4; qs++)
          *(floatx4*)&Of[wv_*2304 + (qs*16+m)*36 + cc*16 + quad*4] = Oc[rd*2+cc][qs];
      }
      __syncthreads();
      floatx4 s0 = (floatx4)0.f, s1 = (floatx4)0.f;
#pragma unroll
      for (int w=0; w<4; w++){
        s0 += *(const floatx4*)&Of[w*2304 + qlr*36 + c8];
        s1 += *(const floatx4*)&Of[w*2304 + qlr*36 + c8 + 4];
      }
      float iv = invL[qlr];
      short8 o;
#pragma unroll
      for (int j=0;j<4;j++){
        o[j]   = (short)f2b(s0[j]*iv);
        o[4+j] = (short)f2b(s1[j]*iv);
      }
      *(short8*)&ob[(size_t)qlr*CD + rd*32 + c8] = o;
      __syncthreads();
    }
  }
#undef STAGE
}

// ---------------------------------------------------------------------------
// out[b,c,hw] = s[b,c,hw] + 0.5*(O1[b,hw,c] + O2[b,hw,c])  (R8 version)
// ---------------------------------------------------------------------------
__global__ __launch_bounds__(256) void combine_kernel(
    const float* __restrict__ s, const unsigned short* __restrict__ Og,
    float* __restrict__ out)
{
  __shared__ __align__(16) float T[32][132];
  const int b   = blockIdx.y;
  const int hw0 = blockIdx.x * 32;
  const int tid = threadIdx.x;
  const unsigned short* O1 = Og + ((size_t)b*HW + hw0)*CD;
  const unsigned short* O2 = O1 + (size_t)NB*HW*CD;
  for (int i=0;i<2;i++){
    int flat = tid + i*256;              // 0..511
    int row = flat >> 4, col0 = (flat & 15)*8;
    short8 a  = *(const short8*)(O1 + (size_t)row*CD + col0);
    short8 c2 = *(const short8*)(O2 + (size_t)row*CD + col0);
    floatx4 v0, v1;
#pragma unroll
    for (int j=0;j<4;j++){
      v0[j] = 0.5f*(b2f((unsigned short)a[j])   + b2f((unsigned short)c2[j]));
      v1[j] = 0.5f*(b2f((unsigned short)a[4+j]) + b2f((unsigned short)c2[4+j]));
    }
    *(floatx4*)&T[row][col0]   = v0;
    *(floatx4*)&T[row][col0+4] = v1;
  }
  __syncthreads();
  const int c  = tid >> 1;
  const int h0 = (tid & 1)*16;
  const float* sr = s   + ((size_t)b*CD + c)*HW + hw0 + h0;
  float*     orow = out + ((size_t)b*CD + c)*HW + hw0 + h0;
  for (int j0=0;j0<16;j0+=4){
    floatx4 sv = *(const floatx4*)(sr + j0);
    floatx4 ov;
    for (int jj=0;jj<4;jj++) ov[jj] = sv[jj] + T[h0+j0+jj][c];
    *(floatx4*)(orow + j0) = ov;
  }
}

extern "C" void kernel_launch(void* const* d_in, const int* in_sizes, int n_in,
                              void* d_out, int out_size, void* d_ws, size_t ws_size,
                              hipStream_t stream)
{
  const float* s  = (const float*)d_in[0];
  const float* t1 = (const float*)d_in[1];
  const float* t2 = (const float*)d_in[2];
  const float* wq = (const float*)d_in[3];
  const float* bq = (const float*)d_in[4];
  const float* wk = (const float*)d_in[5];
  const float* bk = (const float*)d_in[6];
  const float* wv = (const float*)d_in[7];
  const float* bv = (const float*)d_in[8];
  float* out = (float*)d_out;

  unsigned short* qkv = (unsigned short*)d_ws;                 // 5*NB*HW*CD bf16
  unsigned short* Og  = qkv + (size_t)5*NB*HW*CD;              // 2*NB*HW*CD bf16
  unsigned short* Wb  = Og  + (size_t)2*NB*HW*CD;              // 3*CD*CD bf16

  hipLaunchKernelGGL(wconv_kernel,   dim3(3),      dim3(256), 0, stream, wq, wk, wv, Wb);
  hipLaunchKernelGGL(proj_kernel,    dim3(49,8,5), dim3(256), 0, stream,
                     s, t1, t2, bq, bk, bv, Wb, qkv);
  hipLaunchKernelGGL(attn_kernel,    dim3(392),    dim3(256), 0, stream, qkv, Og);
  hipLaunchKernelGGL(combine_kernel, dim3(98,8),   dim3(256), 0, stream, s, Og, out);
}

// Round 11
// 295.247 us; speedup vs baseline: 1.0028x; 1.0028x over previous
//
#include <hip/hip_runtime.h>

#define HW 3136
#define NB 8
#define CD 128
#define NT (HW/64)
// C^-0.5 * log2(e), folded into the Q projection so attn can use exp2 directly
#define QSCALE 0.12751750206f

typedef __attribute__((ext_vector_type(8))) short short8;
typedef __attribute__((ext_vector_type(4))) short short4v;
typedef __attribute__((ext_vector_type(4))) float floatx4;
typedef __attribute__((ext_vector_type(4))) unsigned short ushort4v;

static __device__ __forceinline__ unsigned short f2b(float f){
  union { float f; unsigned u; } v; v.f = f;
  unsigned r = v.u + 0x7FFFu + ((v.u >> 16) & 1u);
  return (unsigned short)(r >> 16);
}
static __device__ __forceinline__ float b2f(unsigned short h){
  union { unsigned u; float f; } v; v.u = ((unsigned)h) << 16;
  return v.f;
}
// packed f32x2 -> bf16x2 (RNE), 1 instr vs 3 bitops; no builtin on gfx950
static __device__ __forceinline__ unsigned cvtpk(float lo, float hi){
  unsigned r;
  asm("v_cvt_pk_bf16_f32 %0, %1, %2" : "=v"(r) : "v"(lo), "v"(hi));
  return r;
}

// K=16 bf16 MFMA: builtin spelling differs across ROCm versions; hedge.
#if __has_builtin(__builtin_amdgcn_mfma_f32_16x16x16bf16_1k)
#define MFMA16(a,b,c) __builtin_amdgcn_mfma_f32_16x16x16bf16_1k(a,b,c,0,0,0)
#elif __has_builtin(__builtin_amdgcn_mfma_f32_16x16x16_bf16)
#define MFMA16(a,b,c) __builtin_amdgcn_mfma_f32_16x16x16_bf16(a,b,c,0,0,0)
#else
static __device__ __forceinline__ floatx4 mfma16_asm(short4v a, short4v b, floatx4 c){
  floatx4 d;
  asm volatile("v_mfma_f32_16x16x16_bf16 %0, %1, %2, %3\n\ts_nop 7\n\ts_nop 7"
               : "=v"(d) : "v"(a), "v"(b), "v"(c));
  return d;
}
#define MFMA16(a,b,c) mfma16_asm(a,b,c)
#endif

// ---------------------------------------------------------------------------
// 1x1 conv projections via MFMA — byte-exact R9-verified version (rest=130).
// R10 zero-LDS variant regressed (rest 130->152); X-staging hypothesis dead.
// ---------------------------------------------------------------------------
__global__ __launch_bounds__(256) void proj_kernel(
    const float* __restrict__ s, const float* __restrict__ t1, const float* __restrict__ t2,
    const float* __restrict__ wq, const float* __restrict__ bq,
    const float* __restrict__ wk, const float* __restrict__ bk,
    const float* __restrict__ wv, const float* __restrict__ bv,
    unsigned short* __restrict__ qkv)
{
  __shared__ __align__(16) unsigned short WL[CD][136];   // W bf16 [o][c]
  __shared__ __align__(16) unsigned short xsT[64][136];  // X^T bf16 [hw_local][c]
  const int job = blockIdx.z;
  const float* x; const float* w; const float* bias; float scl; int cmajor; size_t dstoff;
  switch(job){
    case 0: x=s;  w=wq; bias=bq; scl=QSCALE; cmajor=0; dstoff=0; break;
    case 1: x=t1; w=wk; bias=bk; scl=1.f;    cmajor=0; dstoff=1; break;
    case 2: x=t1; w=wv; bias=bv; scl=1.f;    cmajor=1; dstoff=2; break;
    case 3: x=t2; w=wk; bias=bk; scl=1.f;    cmajor=0; dstoff=3; break;
    default:x=t2; w=wv; bias=bv; scl=1.f;    cmajor=1; dstoff=4; break;
  }
  const size_t TS = (size_t)NB*HW*CD;
  const int b   = blockIdx.y;
  const int hw0 = blockIdx.x * 64;
  const int tid = threadIdx.x;

  // stage W (f32 -> bf16, rounded)
  for (int i = 0; i < 16; i++){
    int flat = tid + i*256;                 // o*32 + cq/4
    int o = flat >> 5, cq = (flat & 31)*4;
    floatx4 wv4 = *(const floatx4*)(w + (size_t)o*CD + cq);
    ushort4v pk;
    for (int j=0;j<4;j++) pk[j] = f2b(wv4[j]);
    *(ushort4v*)&WL[o][cq] = pk;
  }
  // stage X^T (transpose during store)
  const float* xb = x + (size_t)b*CD*HW + hw0;
  for (int i = 0; i < 8; i++){
    int flat = (tid + i*256)*4;             // c*64 + hh
    int c = flat >> 6, hh = flat & 63;
    floatx4 xv = *(const floatx4*)(xb + (size_t)c*HW + hh);
    for (int j=0;j<4;j++) xsT[hh+j][c] = f2b(xv[j]);
  }
  __syncthreads();

  const int m = tid & 15, quad = (tid >> 4) & 3, wv_ = tid >> 6;
  short8 af[4];
#pragma unroll
  for (int dk=0;dk<4;dk++)
    af[dk] = *(const short8*)&xsT[wv_*16 + m][dk*32 + quad*8];

  unsigned short* dstK = qkv + dstoff*TS + ((size_t)b*HW + hw0)*CD;
  unsigned short* dstV = qkv + dstoff*TS + (size_t)b*CD*HW;
  if (!cmajor){
    // swapped operands: D[o][hw]; lane holds o = nt*16+quad*4+r, hw = wv*16+m
#pragma unroll
    for (int nt=0;nt<8;nt++){
      floatx4 acc = *(const floatx4*)(bias + nt*16 + quad*4);
#pragma unroll
      for (int dk=0;dk<4;dk++){
        short8 bf = *(const short8*)&WL[nt*16 + m][dk*32 + quad*8];
        acc = __builtin_amdgcn_mfma_f32_16x16x32_bf16(bf, af[dk], acc, 0,0,0);
      }
      ushort4v pk;
      for (int r=0;r<4;r++) pk[r] = f2b(acc[r]*scl);
      *(ushort4v*)&dstK[(size_t)(wv_*16 + m)*CD + nt*16 + quad*4] = pk;
    }
  } else {
    // original order: D[hw][c]; lane holds 4 hw at fixed c -> [c][hw] 8B stores
    float bb[8];
#pragma unroll
    for (int nt=0;nt<8;nt++) bb[nt] = bias[nt*16 + m];
#pragma unroll
    for (int nt=0;nt<8;nt++){
      floatx4 acc = {bb[nt],bb[nt],bb[nt],bb[nt]};
#pragma unroll
      for (int dk=0;dk<4;dk++){
        short8 bf = *(const short8*)&WL[nt*16 + m][dk*32 + quad*8];
        acc = __builtin_amdgcn_mfma_f32_16x16x32_bf16(af[dk], bf, acc, 0,0,0);
      }
      ushort4v pk;
      for (int r=0;r<4;r++) pk[r] = f2b(acc[r]*scl);
      *(ushort4v*)&dstV[(size_t)(nt*16 + m)*HW + hw0 + wv_*16 + quad*4] = pk;
    }
  }
}

// ---------------------------------------------------------------------------
// Flash attention — R9 structure (T5 setprio + T12 cvtpk, 144.5us) with ONE
// change: K removed from LDS. Each wave reads only the K rows it itself
// staged (rows wv*16+m) — the K LDS round-trip was intra-wave movement with
// zero sharing. af now loads DIRECTLY from global K (16B/lane, 16x64B
// coalesced segments; tile read by all 49 qt-blocks of this b -> L2-hot).
// Removes per iter: 4 K-DMAs, 16KB LDS writes, 4 swizzled ds_read_b128 (the
// main bank-conflict source). LDS 67072 -> 38144B (V-only double buffer).
// Waits: af issued right after B1 (sched-fenced before V-DMAs); manual
// vmcnt(8) = drain prev-tile V only; compiler auto-vmcnt(4) covers af at QK.
// R8 accounting: ~700cyc/iter of stall vs 400 arithmetic -> predicted -10%.
// ---------------------------------------------------------------------------
__global__ __launch_bounds__(256,2) void attn_kernel(
    const unsigned short* __restrict__ qkv,
    unsigned short* __restrict__ Og)
{
  // shorts: V0 [0,8192) V1 [8192,16384); epilogue Of overlaps [0,18432);
  // lrb at byte 36864, invL at 37888. Total 38144 B.
  __shared__ __align__(16) unsigned short smem[18432 + 512 + 128];
  float* lrb  = (float*)(smem + 18432);        // [4 wv][64 q]
  float* invL = (float*)(smem + 18432 + 512);  // [64 q]

  const int l  = blockIdx.x;       // 392 = 8 XCD-pinned b values x 49 qt
  const int b  = l & 7;
  const int qt = l >> 3;
  const size_t TS = (size_t)NB*HW*CD;
  const unsigned short* Q = qkv + (size_t)b*HW*CD;

  const int tid  = threadIdx.x;
  const int wv_  = tid >> 6;
  const int lane = tid & 63;
  const int m    = lane & 15;
  const int quad = lane >> 4;
  const int q0   = qt*64;

  const int      vrow0 = wv_*32 + (lane>>3);
  const unsigned vcs   = (unsigned)(((lane&7) ^ (lane>>3))*8);

  // Q B-fragments, iter- and teacher-invariant
  short8 qf[4][4];
#pragma unroll
  for (int qs=0;qs<4;qs++){
    const unsigned short* qr = Q + (size_t)(q0 + qs*16 + m)*CD + quad*8;
#pragma unroll
    for (int dk=0;dk<4;dk++) qf[qs][dk] = *(const short8*)(qr + dk*32);
  }

#define STAGE(buf, ktile) do { \
    const unsigned short* vt_src = V + (size_t)(ktile)*64; \
    unsigned short* vl = (unsigned short*)smem + (buf)*8192 + wv_*2048; \
    _Pragma("unroll") \
    for (int i_=0;i_<4;i_++) \
      __builtin_amdgcn_global_load_lds( \
        (const __attribute__((address_space(1))) void*)(vt_src + (size_t)(vrow0 + i_*8)*HW + vcs), \
        (__attribute__((address_space(3))) void*)(vl + i_*512), 16, 0, 0); \
  } while(0)

  for (int t2=0; t2<2; t2++){
    const unsigned short* K = qkv + TS*(size_t)(1 + 2*t2) + (size_t)b*HW*CD;
    const unsigned short* V = qkv + TS*(size_t)(2 + 2*t2) + (size_t)b*CD*HW;
    const unsigned short* ka = K + (size_t)(wv_*16 + m)*CD + quad*8;  // own rows

    floatx4 Oc[8][4];                  // k-partial O^T: [ct][qs] (AGPRs)
#pragma unroll
    for (int i=0;i<8;i++)
#pragma unroll
      for (int j=0;j<4;j++) Oc[i][j] = (floatx4)0.f;
    float lr[4] = {0.f,0.f,0.f,0.f};

    STAGE(0, 0);                       // prologue: V tile 0 -> buf0

    for (int kt = 0; kt < NT; kt++){
      const int cur = kt & 1;
      __builtin_amdgcn_s_barrier();    // B1: all waves done reading buf[cur^1]

      // K fragment for THIS tile, direct from global (L2-hot, coalesced).
      short8 af[4];
#pragma unroll
      for (int dk=0;dk<4;dk++)
        af[dk] = *(const short8*)(ka + dk*32);
      ka += 64*CD;
      __builtin_amdgcn_sched_barrier(0);   // keep af issue BEFORE V-DMAs

      if (kt < NT-1){
        STAGE(cur^1, kt+1);            // async DMA next V tile
        asm volatile("s_waitcnt vmcnt(8)" ::: "memory");  // prev V drained
      } else {
        asm volatile("s_waitcnt vmcnt(4)" ::: "memory");  // allow only af
      }
      __builtin_amdgcn_sched_barrier(0);
      __builtin_amdgcn_s_barrier();    // B2: everyone's buf[cur] complete
      asm volatile("" ::: "memory");

      const unsigned short* Vc = (const unsigned short*)smem + cur*8192;

      // QK: S^T[wv's 16k][64q]; A-frag = own-wave K rows (registers)
      short4v pfv[4];
#pragma unroll
      for (int qs=0;qs<4;qs++){
        floatx4 acc = (floatx4)0.f;
        __builtin_amdgcn_s_setprio(1);           // T5: MFMA cluster priority
#pragma unroll
        for (int dk=0;dk<4;dk++)
          acc = __builtin_amdgcn_mfma_f32_16x16x32_bf16(af[dk], qf[qs][dk], acc, 0,0,0);
        __builtin_amdgcn_s_setprio(0);           // exp2 phase at low prio
        float c0 = __builtin_amdgcn_exp2f(acc[0]);
        float c1 = __builtin_amdgcn_exp2f(acc[1]);
        float c2 = __builtin_amdgcn_exp2f(acc[2]);
        float c3 = __builtin_amdgcn_exp2f(acc[3]);
        lr[qs] += (c0 + c1) + (c2 + c3);
        union { unsigned u[2]; short4v s; } pk;
        pk.u[0] = cvtpk(c0, c1);                 // T12: packed RNE convert
        pk.u[1] = cvtpk(c2, c3);
        pfv[qs] = pk.s;
      }

      // PV (K=16): O^T += V^T[c][wv's 16k] * P^T; swizzled b64 A-frag reads
      __builtin_amdgcn_s_setprio(1);             // T5: PV MFMA cluster
#pragma unroll
      for (int ct=0;ct<8;ct++){
        short4v vf = *(const short4v*)&Vc[(ct*16 + m)*64 +
                       (((2*wv_ + (quad>>1)) ^ (m & 7))*8) + (quad&1)*4];
#pragma unroll
        for (int qs=0;qs<4;qs++)
          Oc[ct][qs] = MFMA16(vf, pfv[qs], Oc[ct][qs]);
      }
      __builtin_amdgcn_s_setprio(0);
    }

    // ---- epilogue: cross-wave reduction of lr and O partials ----
#pragma unroll
    for (int qs=0;qs<4;qs++){
      lr[qs] += __shfl_xor(lr[qs], 16, 64);
      lr[qs] += __shfl_xor(lr[qs], 32, 64);
    }
    if (quad == 0){
#pragma unroll
      for (int qs=0;qs<4;qs++) lrb[wv_*64 + qs*16 + m] = lr[qs];
    }
    __syncthreads();
    if (tid < 64)
      invL[tid] = 1.f/(lrb[tid] + lrb[64+tid] + lrb[128+tid] + lrb[192+tid]);
    __syncthreads();

    float* Of = (float*)smem;          // overlaps V buffers (all reads done)
    unsigned short* ob = Og + ((size_t)t2*NB + b)*HW*CD + (size_t)q0*CD;
    const int qlr = wv_*16 + (lane>>2);
    const int c8  = (lane&3)*8;
#pragma unroll
    for (int rd=0; rd<4; rd++){
#pragma unroll
      for (int cc=0; cc<2; cc++){
#pragma unroll
        for (int qs=0; qs<4; qs++)
          *(floatx4*)&Of[wv_*2304 + (qs*16+m)*36 + cc*16 + quad*4] = Oc[rd*2+cc][qs];
      }
      __syncthreads();
      floatx4 s0 = (floatx4)0.f, s1 = (floatx4)0.f;
#pragma unroll
      for (int w=0; w<4; w++){
        s0 += *(const floatx4*)&Of[w*2304 + qlr*36 + c8];
        s1 += *(const floatx4*)&Of[w*2304 + qlr*36 + c8 + 4];
      }
      float iv = invL[qlr];
      short8 o;
#pragma unroll
      for (int j=0;j<4;j++){
        o[j]   = (short)f2b(s0[j]*iv);
        o[4+j] = (short)f2b(s1[j]*iv);
      }
      *(short8*)&ob[(size_t)qlr*CD + rd*32 + c8] = o;
      __syncthreads();
    }
  }
#undef STAGE
}

// ---------------------------------------------------------------------------
// out[b,c,hw] = s[b,c,hw] + 0.5*(O1[b,hw,c] + O2[b,hw,c])  (R8/R9 version)
// ---------------------------------------------------------------------------
__global__ __launch_bounds__(256) void combine_kernel(
    const float* __restrict__ s, const unsigned short* __restrict__ Og,
    float* __restrict__ out)
{
  __shared__ __align__(16) float T[32][132];
  const int b   = blockIdx.y;
  const int hw0 = blockIdx.x * 32;
  const int tid = threadIdx.x;
  const unsigned short* O1 = Og + ((size_t)b*HW + hw0)*CD;
  const unsigned short* O2 = O1 + (size_t)NB*HW*CD;
  for (int i=0;i<2;i++){
    int flat = tid + i*256;              // 0..511
    int row = flat >> 4, col0 = (flat & 15)*8;
    short8 a  = *(const short8*)(O1 + (size_t)row*CD + col0);
    short8 c2 = *(const short8*)(O2 + (size_t)row*CD + col0);
    floatx4 v0, v1;
#pragma unroll
    for (int j=0;j<4;j++){
      v0[j] = 0.5f*(b2f((unsigned short)a[j])   + b2f((unsigned short)c2[j]));
      v1[j] = 0.5f*(b2f((unsigned short)a[4+j]) + b2f((unsigned short)c2[4+j]));
    }
    *(floatx4*)&T[row][col0]   = v0;
    *(floatx4*)&T[row][col0+4] = v1;
  }
  __syncthreads();
  const int c  = tid >> 1;
  const int h0 = (tid & 1)*16;
  const float* sr = s   + ((size_t)b*CD + c)*HW + hw0 + h0;
  float*     orow = out + ((size_t)b*CD + c)*HW + hw0 + h0;
  for (int j0=0;j0<16;j0+=4){
    floatx4 sv = *(const floatx4*)(sr + j0);
    floatx4 ov;
    for (int jj=0;jj<4;jj++) ov[jj] = sv[jj] + T[h0+j0+jj][c];
    *(floatx4*)(orow + j0) = ov;
  }
}

extern "C" void kernel_launch(void* const* d_in, const int* in_sizes, int n_in,
                              void* d_out, int out_size, void* d_ws, size_t ws_size,
                              hipStream_t stream)
{
  const float* s  = (const float*)d_in[0];
  const float* t1 = (const float*)d_in[1];
  const float* t2 = (const float*)d_in[2];
  const float* wq = (const float*)d_in[3];
  const float* bq = (const float*)d_in[4];
  const float* wk = (const float*)d_in[5];
  const float* bk = (const float*)d_in[6];
  const float* wv = (const float*)d_in[7];
  const float* bv = (const float*)d_in[8];
  float* out = (float*)d_out;

  unsigned short* qkv = (unsigned short*)d_ws;                 // 5*NB*HW*CD bf16
  unsigned short* Og  = qkv + (size_t)5*NB*HW*CD;              // 2*NB*HW*CD bf16

  hipLaunchKernelGGL(proj_kernel,    dim3(49,8,5), dim3(256), 0, stream,
                     s,t1,t2,wq,bq,wk,bk,wv,bv,qkv);
  hipLaunchKernelGGL(attn_kernel,    dim3(392),    dim3(256), 0, stream, qkv, Og);
  hipLaunchKernelGGL(combine_kernel, dim3(98,8),   dim3(256), 0, stream, s, Og, out);
}

// Round 12
// 277.660 us; speedup vs baseline: 1.0663x; 1.0633x over previous
//
#include <hip/hip_runtime.h>

#define HW 3136
#define NB 8
#define CD 128
#define NT (HW/64)
// C^-0.5 * log2(e), folded into the Q projection so attn can use exp2 directly
#define QSCALE 0.12751750206f

typedef __attribute__((ext_vector_type(8))) short short8;
typedef __attribute__((ext_vector_type(4))) short short4v;
typedef __attribute__((ext_vector_type(4))) float floatx4;
typedef __attribute__((ext_vector_type(4))) unsigned short ushort4v;

static __device__ __forceinline__ unsigned short f2b(float f){
  union { float f; unsigned u; } v; v.f = f;
  unsigned r = v.u + 0x7FFFu + ((v.u >> 16) & 1u);
  return (unsigned short)(r >> 16);
}
static __device__ __forceinline__ float b2f(unsigned short h){
  union { unsigned u; float f; } v; v.u = ((unsigned)h) << 16;
  return v.f;
}
// packed f32x2 -> bf16x2 (RNE), 1 instr vs 3 bitops; no builtin on gfx950
static __device__ __forceinline__ unsigned cvtpk(float lo, float hi){
  unsigned r;
  asm("v_cvt_pk_bf16_f32 %0, %1, %2" : "=v"(r) : "v"(lo), "v"(hi));
  return r;
}

// K=16 bf16 MFMA: builtin spelling differs across ROCm versions; hedge.
#if __has_builtin(__builtin_amdgcn_mfma_f32_16x16x16bf16_1k)
#define MFMA16(a,b,c) __builtin_amdgcn_mfma_f32_16x16x16bf16_1k(a,b,c,0,0,0)
#elif __has_builtin(__builtin_amdgcn_mfma_f32_16x16x16_bf16)
#define MFMA16(a,b,c) __builtin_amdgcn_mfma_f32_16x16x16_bf16(a,b,c,0,0,0)
#else
static __device__ __forceinline__ floatx4 mfma16_asm(short4v a, short4v b, floatx4 c){
  floatx4 d;
  asm volatile("v_mfma_f32_16x16x16_bf16 %0, %1, %2, %3\n\ts_nop 7\n\ts_nop 7"
               : "=v"(d) : "v"(a), "v"(b), "v"(c));
  return d;
}
#define MFMA16(a,b,c) mfma16_asm(a,b,c)
#endif

// ---------------------------------------------------------------------------
// 1x1 conv projections via MFMA — R9-verified version (rest=130; every
// alternative tested R6-R11 came back null or worse).
// ---------------------------------------------------------------------------
__global__ __launch_bounds__(256) void proj_kernel(
    const float* __restrict__ s, const float* __restrict__ t1, const float* __restrict__ t2,
    const float* __restrict__ wq, const float* __restrict__ bq,
    const float* __restrict__ wk, const float* __restrict__ bk,
    const float* __restrict__ wv, const float* __restrict__ bv,
    unsigned short* __restrict__ qkv)
{
  __shared__ __align__(16) unsigned short WL[CD][136];   // W bf16 [o][c]
  __shared__ __align__(16) unsigned short xsT[64][136];  // X^T bf16 [hw_local][c]
  const int job = blockIdx.z;
  const float* x; const float* w; const float* bias; float scl; int cmajor; size_t dstoff;
  switch(job){
    case 0: x=s;  w=wq; bias=bq; scl=QSCALE; cmajor=0; dstoff=0; break;
    case 1: x=t1; w=wk; bias=bk; scl=1.f;    cmajor=0; dstoff=1; break;
    case 2: x=t1; w=wv; bias=bv; scl=1.f;    cmajor=1; dstoff=2; break;
    case 3: x=t2; w=wk; bias=bk; scl=1.f;    cmajor=0; dstoff=3; break;
    default:x=t2; w=wv; bias=bv; scl=1.f;    cmajor=1; dstoff=4; break;
  }
  const size_t TS = (size_t)NB*HW*CD;
  const int b   = blockIdx.y;
  const int hw0 = blockIdx.x * 64;
  const int tid = threadIdx.x;

  // stage W (f32 -> bf16, rounded)
  for (int i = 0; i < 16; i++){
    int flat = tid + i*256;                 // o*32 + cq/4
    int o = flat >> 5, cq = (flat & 31)*4;
    floatx4 wv4 = *(const floatx4*)(w + (size_t)o*CD + cq);
    ushort4v pk;
    for (int j=0;j<4;j++) pk[j] = f2b(wv4[j]);
    *(ushort4v*)&WL[o][cq] = pk;
  }
  // stage X^T (transpose during store)
  const float* xb = x + (size_t)b*CD*HW + hw0;
  for (int i = 0; i < 8; i++){
    int flat = (tid + i*256)*4;             // c*64 + hh
    int c = flat >> 6, hh = flat & 63;
    floatx4 xv = *(const floatx4*)(xb + (size_t)c*HW + hh);
    for (int j=0;j<4;j++) xsT[hh+j][c] = f2b(xv[j]);
  }
  __syncthreads();

  const int m = tid & 15, quad = (tid >> 4) & 3, wv_ = tid >> 6;
  short8 af[4];
#pragma unroll
  for (int dk=0;dk<4;dk++)
    af[dk] = *(const short8*)&xsT[wv_*16 + m][dk*32 + quad*8];

  unsigned short* dstK = qkv + dstoff*TS + ((size_t)b*HW + hw0)*CD;
  unsigned short* dstV = qkv + dstoff*TS + (size_t)b*CD*HW;
  if (!cmajor){
    // swapped operands: D[o][hw]; lane holds o = nt*16+quad*4+r, hw = wv*16+m
#pragma unroll
    for (int nt=0;nt<8;nt++){
      floatx4 acc = *(const floatx4*)(bias + nt*16 + quad*4);
#pragma unroll
      for (int dk=0;dk<4;dk++){
        short8 bf = *(const short8*)&WL[nt*16 + m][dk*32 + quad*8];
        acc = __builtin_amdgcn_mfma_f32_16x16x32_bf16(bf, af[dk], acc, 0,0,0);
      }
      ushort4v pk;
      for (int r=0;r<4;r++) pk[r] = f2b(acc[r]*scl);
      *(ushort4v*)&dstK[(size_t)(wv_*16 + m)*CD + nt*16 + quad*4] = pk;
    }
  } else {
    // original order: D[hw][c]; lane holds 4 hw at fixed c -> [c][hw] 8B stores
    float bb[8];
#pragma unroll
    for (int nt=0;nt<8;nt++) bb[nt] = bias[nt*16 + m];
#pragma unroll
    for (int nt=0;nt<8;nt++){
      floatx4 acc = {bb[nt],bb[nt],bb[nt],bb[nt]};
#pragma unroll
      for (int dk=0;dk<4;dk++){
        short8 bf = *(const short8*)&WL[nt*16 + m][dk*32 + quad*8];
        acc = __builtin_amdgcn_mfma_f32_16x16x32_bf16(af[dk], bf, acc, 0,0,0);
      }
      ushort4v pk;
      for (int r=0;r<4;r++) pk[r] = f2b(acc[r]*scl);
      *(ushort4v*)&dstV[(size_t)(nt*16 + m)*HW + hw0 + wv_*16 + quad*4] = pk;
    }
  }
}

// ---------------------------------------------------------------------------
// Flash attention — R9-verified (144.5us): R4 k-split DMA double-buffer
// structure + T5 setprio around MFMA clusters + T12 cvt_pk RNE packing.
// R11's K-direct variant regressed (156us): DMA staging hides L2 latency
// across barriers; register K-loads don't.
// ---------------------------------------------------------------------------
__global__ __launch_bounds__(256,2) void attn_kernel(
    const unsigned short* __restrict__ qkv,
    unsigned short* __restrict__ Og)
{
  // shorts: K0 [0,8192) V0 [8192,16384) K1 [16384,24576) V1 [24576,32768)
  __shared__ __align__(16) unsigned short smem[32768 + 512 + 128]; // 66816 B
  float* lrb  = (float*)(smem + 32768);        // [4 wv][64 q]
  float* invL = (float*)(smem + 32768 + 512);  // [64 q]

  const int l  = blockIdx.x;       // 392 = 8 XCD-pinned b values x 49 qt
  const int b  = l & 7;
  const int qt = l >> 3;
  const size_t TS = (size_t)NB*HW*CD;
  const unsigned short* Q = qkv + (size_t)b*HW*CD;

  const int tid  = threadIdx.x;
  const int wv_  = tid >> 6;
  const int lane = tid & 63;
  const int m    = lane & 15;
  const int quad = lane >> 4;
  const int q0   = qt*64;

  // DMA source offsets (shorts), pre-swizzled so linear LDS dest + swizzled
  // ds_read agree: LDS(row, col16) holds logical col16 ^ (row&7).
  unsigned koff[4];
  {
    const int kr_ = lane >> 4, kc_ = lane & 15;
#pragma unroll
    for (int i=0;i<4;i++){
      const int krow = wv_*16 + i*4 + kr_;
      koff[i] = (unsigned)(krow*CD + ((kc_ ^ ((i*4 + kr_) & 7))*8));
    }
  }
  const int      vrow0 = wv_*32 + (lane>>3);
  const unsigned vcs   = (unsigned)(((lane&7) ^ (lane>>3))*8);

  // Q B-fragments, iter- and teacher-invariant
  short8 qf[4][4];
#pragma unroll
  for (int qs=0;qs<4;qs++){
    const unsigned short* qr = Q + (size_t)(q0 + qs*16 + m)*CD + quad*8;
#pragma unroll
    for (int dk=0;dk<4;dk++) qf[qs][dk] = *(const short8*)(qr + dk*32);
  }

#define STAGE(buf, ktile) do { \
    const unsigned short* kt_src = K + (size_t)(ktile)*64*CD; \
    const unsigned short* vt_src = V + (size_t)(ktile)*64; \
    unsigned short* kl = (unsigned short*)smem + (buf)*16384 + wv_*2048; \
    unsigned short* vl = (unsigned short*)smem + (buf)*16384 + 8192 + wv_*2048; \
    _Pragma("unroll") \
    for (int i_=0;i_<4;i_++) \
      __builtin_amdgcn_global_load_lds( \
        (const __attribute__((address_space(1))) void*)(kt_src + koff[i_]), \
        (__attribute__((address_space(3))) void*)(kl + i_*512), 16, 0, 0); \
    _Pragma("unroll") \
    for (int i_=0;i_<4;i_++) \
      __builtin_amdgcn_global_load_lds( \
        (const __attribute__((address_space(1))) void*)(vt_src + (size_t)(vrow0 + i_*8)*HW + vcs), \
        (__attribute__((address_space(3))) void*)(vl + i_*512), 16, 0, 0); \
  } while(0)

  for (int t2=0; t2<2; t2++){
    const unsigned short* K = qkv + TS*(size_t)(1 + 2*t2) + (size_t)b*HW*CD;
    const unsigned short* V = qkv + TS*(size_t)(2 + 2*t2) + (size_t)b*CD*HW;

    floatx4 Oc[8][4];                  // k-partial O^T: [ct][qs] (AGPRs)
#pragma unroll
    for (int i=0;i<8;i++)
#pragma unroll
      for (int j=0;j<4;j++) Oc[i][j] = (floatx4)0.f;
    float lr[4] = {0.f,0.f,0.f,0.f};

    STAGE(0, 0);                       // prologue: tile 0 -> buf0

    for (int kt = 0; kt < NT; kt++){
      const int cur = kt & 1;
      __builtin_amdgcn_s_barrier();    // B1: all waves done computing buf[cur^1]
      if (kt < NT-1){
        STAGE(cur^1, kt+1);            // async DMA next tile
        asm volatile("s_waitcnt vmcnt(8)" ::: "memory");  // own buf[cur] DMAs done
      } else {
        asm volatile("s_waitcnt vmcnt(0)" ::: "memory");
      }
      __builtin_amdgcn_sched_barrier(0);
      __builtin_amdgcn_s_barrier();    // B2: everyone's buf[cur] complete
      asm volatile("" ::: "memory");

      const unsigned short* Kc = (const unsigned short*)smem + cur*16384;
      const unsigned short* Vc = (const unsigned short*)smem + cur*16384 + 8192;

      // QK: S^T[wv's 16k][64q]; A-frag = own-wave K rows, swizzled read
      short8 af[4];
#pragma unroll
      for (int dk=0;dk<4;dk++)
        af[dk] = *(const short8*)&Kc[(wv_*16 + m)*128 + (((dk*4 + quad) ^ (m & 7))*8)];

      short4v pfv[4];
#pragma unroll
      for (int qs=0;qs<4;qs++){
        floatx4 acc = (floatx4)0.f;
        __builtin_amdgcn_s_setprio(1);           // T5: MFMA cluster priority
#pragma unroll
        for (int dk=0;dk<4;dk++)
          acc = __builtin_amdgcn_mfma_f32_16x16x32_bf16(af[dk], qf[qs][dk], acc, 0,0,0);
        __builtin_amdgcn_s_setprio(0);           // exp2 phase at low prio
        float c0 = __builtin_amdgcn_exp2f(acc[0]);
        float c1 = __builtin_amdgcn_exp2f(acc[1]);
        float c2 = __builtin_amdgcn_exp2f(acc[2]);
        float c3 = __builtin_amdgcn_exp2f(acc[3]);
        lr[qs] += (c0 + c1) + (c2 + c3);
        union { unsigned u[2]; short4v s; } pk;
        pk.u[0] = cvtpk(c0, c1);                 // T12: packed RNE convert
        pk.u[1] = cvtpk(c2, c3);
        pfv[qs] = pk.s;
      }

      // PV (K=16): O^T += V^T[c][wv's 16k] * P^T; swizzled b64 A-frag reads
      __builtin_amdgcn_s_setprio(1);             // T5: PV MFMA cluster
#pragma unroll
      for (int ct=0;ct<8;ct++){
        short4v vf = *(const short4v*)&Vc[(ct*16 + m)*64 +
                       (((2*wv_ + (quad>>1)) ^ (m & 7))*8) + (quad&1)*4];
#pragma unroll
        for (int qs=0;qs<4;qs++)
          Oc[ct][qs] = MFMA16(vf, pfv[qs], Oc[ct][qs]);
      }
      __builtin_amdgcn_s_setprio(0);
    }

    // ---- epilogue: cross-wave reduction of lr and O partials ----
#pragma unroll
    for (int qs=0;qs<4;qs++){
      lr[qs] += __shfl_xor(lr[qs], 16, 64);
      lr[qs] += __shfl_xor(lr[qs], 32, 64);
    }
    if (quad == 0){
#pragma unroll
      for (int qs=0;qs<4;qs++) lrb[wv_*64 + qs*16 + m] = lr[qs];
    }
    __syncthreads();
    if (tid < 64)
      invL[tid] = 1.f/(lrb[tid] + lrb[64+tid] + lrb[128+tid] + lrb[192+tid]);
    __syncthreads();

    float* Of = (float*)smem;          // overlaps K/V buffers (all reads done)
    unsigned short* ob = Og + ((size_t)t2*NB + b)*HW*CD + (size_t)q0*CD;
    const int qlr = wv_*16 + (lane>>2);
    const int c8  = (lane&3)*8;
#pragma unroll
    for (int rd=0; rd<4; rd++){
#pragma unroll
      for (int cc=0; cc<2; cc++){
#pragma unroll
        for (int qs=0; qs<4; qs++)
          *(floatx4*)&Of[wv_*2304 + (qs*16+m)*36 + cc*16 + quad*4] = Oc[rd*2+cc][qs];
      }
      __syncthreads();
      floatx4 s0 = (floatx4)0.f, s1 = (floatx4)0.f;
#pragma unroll
      for (int w=0; w<4; w++){
        s0 += *(const floatx4*)&Of[w*2304 + qlr*36 + c8];
        s1 += *(const floatx4*)&Of[w*2304 + qlr*36 + c8 + 4];
      }
      float iv = invL[qlr];
      short8 o;
#pragma unroll
      for (int j=0;j<4;j++){
        o[j]   = (short)f2b(s0[j]*iv);
        o[4+j] = (short)f2b(s1[j]*iv);
      }
      *(short8*)&ob[(size_t)qlr*CD + rd*32 + c8] = o;
      __syncthreads();
    }
  }
#undef STAGE
}

// ---------------------------------------------------------------------------
// out[b,c,hw] = s[b,c,hw] + 0.5*(O1[b,hw,c] + O2[b,hw,c])  (R9-verified)
// ---------------------------------------------------------------------------
__global__ __launch_bounds__(256) void combine_kernel(
    const float* __restrict__ s, const unsigned short* __restrict__ Og,
    float* __restrict__ out)
{
  __shared__ __align__(16) float T[32][132];
  const int b   = blockIdx.y;
  const int hw0 = blockIdx.x * 32;
  const int tid = threadIdx.x;
  const unsigned short* O1 = Og + ((size_t)b*HW + hw0)*CD;
  const unsigned short* O2 = O1 + (size_t)NB*HW*CD;
  for (int i=0;i<2;i++){
    int flat = tid + i*256;              // 0..511
    int row = flat >> 4, col0 = (flat & 15)*8;
    short8 a  = *(const short8*)(O1 + (size_t)row*CD + col0);
    short8 c2 = *(const short8*)(O2 + (size_t)row*CD + col0);
    floatx4 v0, v1;
#pragma unroll
    for (int j=0;j<4;j++){
      v0[j] = 0.5f*(b2f((unsigned short)a[j])   + b2f((unsigned short)c2[j]));
      v1[j] = 0.5f*(b2f((unsigned short)a[4+j]) + b2f((unsigned short)c2[4+j]));
    }
    *(floatx4*)&T[row][col0]   = v0;
    *(floatx4*)&T[row][col0+4] = v1;
  }
  __syncthreads();
  const int c  = tid >> 1;
  const int h0 = (tid & 1)*16;
  const float* sr = s   + ((size_t)b*CD + c)*HW + hw0 + h0;
  float*     orow = out + ((size_t)b*CD + c)*HW + hw0 + h0;
  for (int j0=0;j0<16;j0+=4){
    floatx4 sv = *(const floatx4*)(sr + j0);
    floatx4 ov;
    for (int jj=0;jj<4;jj++) ov[jj] = sv[jj] + T[h0+j0+jj][c];
    *(floatx4*)(orow + j0) = ov;
  }
}

extern "C" void kernel_launch(void* const* d_in, const int* in_sizes, int n_in,
                              void* d_out, int out_size, void* d_ws, size_t ws_size,
                              hipStream_t stream)
{
  const float* s  = (const float*)d_in[0];
  const float* t1 = (const float*)d_in[1];
  const float* t2 = (const float*)d_in[2];
  const float* wq = (const float*)d_in[3];
  const float* bq = (const float*)d_in[4];
  const float* wk = (const float*)d_in[5];
  const float* bk = (const float*)d_in[6];
  const float* wv = (const float*)d_in[7];
  const float* bv = (const float*)d_in[8];
  float* out = (float*)d_out;

  unsigned short* qkv = (unsigned short*)d_ws;                 // 5*NB*HW*CD bf16
  unsigned short* Og  = qkv + (size_t)5*NB*HW*CD;              // 2*NB*HW*CD bf16

  hipLaunchKernelGGL(proj_kernel,    dim3(49,8,5), dim3(256), 0, stream,
                     s,t1,t2,wq,bq,wk,bk,wv,bv,qkv);
  hipLaunchKernelGGL(attn_kernel,    dim3(392),    dim3(256), 0, stream, qkv, Og);
  hipLaunchKernelGGL(combine_kernel, dim3(98,8),   dim3(256), 0, stream, s, Og, out);
}